// Round 8
// baseline (380.726 us; speedup 1.0000x reference)
//
#include <hip/hip_runtime.h>
#include <cstdint>
#include <cstddef>

#define T_STEPS 50
#define B_SZ    1024
#define N_INP   784
#define H_SZ    256
#define L_SZ    10
#define M_TOT   (T_STEPS * B_SZ)   // 51200
#define NK0     26                 // K padded to 26*32 = 832
#define NSLICE  5                  // 5 balanced base-256 digits of rint(Wi*2^40): exact (|Wi|<0.5)

typedef int v4i  __attribute__((ext_vector_type(4)));
typedef int v16i __attribute__((ext_vector_type(16)));

// ---------------------------------------------------------------------------
// Phase 0 (merged): blocks 0..63 transpose Wr -> WrTz (+ zero row 256);
// blocks 64..115 pack Wi -> 5 balanced int8 digits (R5/R6-verified exact).
// One dispatch instead of two (saves a launch gap).
// ---------------------------------------------------------------------------
__global__ __launch_bounds__(256) void prep_all(const float* __restrict__ Wr,
                                                float* __restrict__ WrTz,
                                                const float* __restrict__ Wi,
                                                uint8_t* __restrict__ SBp) {
    const int blk = blockIdx.x;
    const int tid = threadIdx.x;
    if (blk < 64) {
        // ---- transpose Wr[h][k] (256x256) -> WrTz[k][h] ----
        __shared__ float tile[32][33];
        int bx = (blk & 7) * 32, by = (blk >> 3) * 32;
        int tx = tid % 32, ty = tid / 32;   // 32 x 8
        #pragma unroll
        for (int j = 0; j < 32; j += 8)
            tile[ty + j][tx] = Wr[(size_t)(by + ty + j) * H_SZ + bx + tx];
        if (blk == 0)
            WrTz[(size_t)256 * H_SZ + tid] = 0.0f;   // dummy zero row
        __syncthreads();
        #pragma unroll
        for (int j = 0; j < 32; j += 8)
            WrTz[(size_t)(bx + ty + j) * H_SZ + by + tx] = tile[tx][ty + j];
    } else {
        // ---- Wi -> digits, fragment-linear ----
        const int unit = (blk - 64) * 4 + (tid >> 6);   // 0..207 = (nt,k0)
        const int nt   = unit / 26;
        const int k0   = unit % 26;
        const int lane = tid & 63;
        const int h    = nt * 32 + (lane & 31);
        const int g    = k0 * 2 + (lane >> 5);          // 16-float group index

        int wd[NSLICE][4] = {};
        #pragma unroll
        for (int u = 0; u < 16; ++u) {
            double wv = 0.0;
            if (g < 49) wv = (double)Wi[(size_t)h * N_INP + g * 16 + u];
            double r = rint(wv * 0x1p40);
            #pragma unroll
            for (int j = 0; j < NSLICE - 1; ++j) {
                double q  = floor((r + 128.0) * 0.00390625);
                double dj = r - 256.0 * q;                     // in [-128,127]
                wd[j][u >> 2] |= ((int)dj & 0xFF) << ((u & 3) * 8);
                r = q;
            }
            wd[NSLICE - 1][u >> 2] |= ((int)r & 0xFF) << ((u & 3) * 8);
        }
        uint8_t* base = SBp + ((size_t)(nt * NK0 + k0) * NSLICE) * 1024 + lane * 16;
        #pragma unroll
        for (int j = 0; j < NSLICE; ++j)
            *(v4i*)(base + (size_t)j * 1024) = (v4i){wd[j][0], wd[j][1], wd[j][2], wd[j][3]};
    }
}

// ---------------------------------------------------------------------------
// Phase 0c: pack X (binary fp32) -> fragment-linear int8 (R6-verified).
// ---------------------------------------------------------------------------
__global__ __launch_bounds__(256) void pack_x(const float* __restrict__ X,
                                              uint8_t* __restrict__ Ap) {
    const int mt  = blockIdx.x;       // 1600
    const int tid = threadIdx.x;
    #pragma unroll
    for (int i = 0; i < 7; ++i) {
        int s = tid + i * 256;
        if (s < NK0 * 64) {
            int k0 = s >> 6, lane = s & 63;
            int m = mt * 32 + (lane & 31);
            int g = k0 * 2 + (lane >> 5);
            unsigned int bw[4] = {0u, 0u, 0u, 0u};
            if (g < 49) {
                const float* src = X + (size_t)m * N_INP + g * 16;
                #pragma unroll
                for (int q = 0; q < 4; ++q) {
                    float4 f = *(const float4*)(src + q * 4);
                    bw[q] = (f.x != 0.f ? 1u : 0u) | (f.y != 0.f ? 0x100u : 0u)
                          | (f.z != 0.f ? 0x10000u : 0u) | (f.w != 0.f ? 0x1000000u : 0u);
                }
            }
            *(v4i*)(Ap + ((size_t)(mt * NK0 + k0)) * 1024 + lane * 16) =
                (v4i){(int)bw[0], (int)bw[1], (int)bw[2], (int)bw[3]};
        }
    }
}

// ---------------------------------------------------------------------------
// Phase 1 v5: cur = X @ Wi.T exactly via 5 int8-digit MFMAs.
// v2 (R3): B staged via global_load_lds width=16. v3 (R5): launch_bounds(256,2)
// -> 2 blocks/CU. v4 (R6): XCD-aware swizzle. v5 (this round): 8-k0 stages
// (2 x 40 KB LDS = 80 KB/block, 2 blocks/CU = 160 KB exactly) -> 4 barriers
// instead of 7. A-loads pipelined in three 4-k0 register batches (a/a2/n,
// 48 VGPR; total ~233 <= 256 keeps 2 waves/SIMD). Ascending-k0 integer
// accumulation unchanged -> cur bit-identical.
// ---------------------------------------------------------------------------
typedef __attribute__((address_space(1))) uint32_t glds_g;
typedef __attribute__((address_space(3))) uint32_t glds_l;

#define STAGE_B(dstbuf, srcp, NI)                                               \
    {                                                                           \
        _Pragma("unroll")                                                       \
        for (int j_ = 0; j_ < (NI); ++j_) {                                     \
            int s_ = j_ * 256 + tid;                                            \
            __builtin_amdgcn_global_load_lds(                                   \
                (glds_g*)((srcp) + (size_t)s_ * 16),                            \
                (glds_l*)((dstbuf) + (size_t)s_ * 16), 16, 0, 0);               \
        }                                                                       \
    }

// HALF = 0 or 1 selects k0 sub-range [HALF*4, HALF*4+NK) within the 8-k0 stage
#define MFMA_HALF(CB, HALF, A0, A1, NK)                                         \
    _Pragma("unroll")                                                           \
    for (int dk = 0; dk < (NK); ++dk) {                                         \
        _Pragma("unroll")                                                       \
        for (int j = 0; j < NSLICE; ++j) {                                      \
            v4i b = *(const v4i*)(Bs[CB] + (((HALF) * 4 + dk) * NSLICE + j) * 1024 + lane * 16); \
            acc0[j] = __builtin_amdgcn_mfma_i32_32x32x32_i8(A0[dk], b, acc0[j], 0, 0, 0); \
            acc1[j] = __builtin_amdgcn_mfma_i32_32x32x32_i8(A1[dk], b, acc1[j], 0, 0, 0); \
        }                                                                       \
    }

__global__ __launch_bounds__(256, 2) void gemm_i8s(const uint8_t* __restrict__ Ap,
                                                   const uint8_t* __restrict__ SBp,
                                                   double* __restrict__ cur) {
    __shared__ __align__(16) uint8_t Bs[2][8 * NSLICE * 1024];   // 2 x 40 KB

    const int tid   = threadIdx.x;
    const int wave  = tid >> 6;
    const int lane  = tid & 63;
    const int ghalf = lane >> 5;

    // XCD-aware swizzle: id = xcd + 8*slot, slot = (x%25)*8 + nt -> xcd = x/25
    const int id   = blockIdx.x;          // 0..1599
    const int xcd  = id & 7;
    const int slot = id >> 3;             // 0..199
    const int x    = xcd * 25 + (slot >> 3);
    const int nt   = slot & 7;

    const int mt0   = (x * 4 + wave) * 2;     // wave owns mt0, mt0+1
    const int mt1   = mt0 + 1;

    const uint8_t* ap0 = Ap + (size_t)mt0 * NK0 * 1024 + lane * 16;
    const uint8_t* ap1 = Ap + (size_t)mt1 * NK0 * 1024 + lane * 16;
    const uint8_t* bbase = SBp + ((size_t)nt * NK0 * NSLICE) * 1024;

    v4i a0[4], a1[4], b0[4], b1[4], n0[4], n1[4];

    // prologue: stage stage-0 (k0 0..7), prefetch A k0 0..3
    STAGE_B(Bs[0], bbase, 10);
    #pragma unroll
    for (int dk = 0; dk < 4; ++dk) {
        a0[dk] = *(const v4i*)(ap0 + (size_t)dk * 1024);
        a1[dk] = *(const v4i*)(ap1 + (size_t)dk * 1024);
    }
    __syncthreads();                       // stage-0 resident

    v16i acc0[NSLICE] = {};
    v16i acc1[NSLICE] = {};

    for (int s = 0; s < 3; ++s) {          // full 8-k0 stages at k0 = 8s
        const int cb = s & 1;
        // stage next buffer: s<2 full 8-k0 (40 KB); s==2 tail k0 24..25
        // (12 KB incl. 2 KB pad that overreads into adjacent Ap region — valid)
        STAGE_B(Bs[cb ^ 1], bbase + (size_t)(s + 1) * 40960, (s < 2) ? 10 : 3);
        // A second half of current stage (k0 8s+4..7)
        #pragma unroll
        for (int dk = 0; dk < 4; ++dk) {
            b0[dk] = *(const v4i*)(ap0 + (size_t)(s * 8 + 4 + dk) * 1024);
            b1[dk] = *(const v4i*)(ap1 + (size_t)(s * 8 + 4 + dk) * 1024);
        }
        MFMA_HALF(cb, 0, a0, a1, 4);
        // A first chunk of next stage (s<2: 4 regs; s==2: tail k0 24..25)
        #pragma unroll
        for (int dk = 0; dk < 4; ++dk) {
            if (dk < ((s < 2) ? 4 : 2)) {
                n0[dk] = *(const v4i*)(ap0 + (size_t)((s + 1) * 8 + dk) * 1024);
                n1[dk] = *(const v4i*)(ap1 + (size_t)((s + 1) * 8 + dk) * 1024);
            }
        }
        MFMA_HALF(cb, 1, b0, b1, 4);
        __syncthreads();                   // next buffer resident
        #pragma unroll
        for (int dk = 0; dk < 4; ++dk) { a0[dk] = n0[dk]; a1[dk] = n1[dk]; }
    }
    // tail: k0 24..25 in Bs[1] (staged during s==2, cb=0 -> cb^1 = 1)
    MFMA_HALF(1, 0, a0, a1, 2);

    // recombine digits (exact integer Horner in fp64) and store both m-tiles
    const int h = nt * 32 + (lane & 31);
    #pragma unroll
    for (int r = 0; r < 16; ++r) {
        int mloc = (r & 3) + 8 * (r >> 2) + 4 * ghalf;
        double s0 = (double)acc0[4][r];
        s0 = s0 * 256.0 + (double)acc0[3][r];
        s0 = s0 * 256.0 + (double)acc0[2][r];
        s0 = s0 * 256.0 + (double)acc0[1][r];
        s0 = s0 * 256.0 + (double)acc0[0][r];
        cur[(size_t)(mt0 * 32 + mloc) * H_SZ + h] = s0 * 0x1p-40;
        double s1 = (double)acc1[4][r];
        s1 = s1 * 256.0 + (double)acc1[3][r];
        s1 = s1 * 256.0 + (double)acc1[2][r];
        s1 = s1 * 256.0 + (double)acc1[1][r];
        s1 = s1 * 256.0 + (double)acc1[0][r];
        cur[(size_t)(mt1 * 32 + mloc) * H_SZ + h] = s1 * 0x1p-40;
    }
}

// ---------------------------------------------------------------------------
// Phase 2 (v2, locked — best measured scan, ~88 µs; three restructures all
// regressed): 50 LIF steps fp64, block = batch (256 thr = 4 waves). ONE
// barrier per step: ballot masks ping-pong; each wave builds a PRIVATE padded
// spike list; entries pre-scaled to row byte offsets; 2x ds_read_b128 per 8.
// ---------------------------------------------------------------------------
__global__ __launch_bounds__(256) void snn_scan(const double* __restrict__ cur,
                                                const float* __restrict__ WrTz,
                                                const float* __restrict__ Wout,
                                                const float* __restrict__ bout,
                                                float* __restrict__ out) {
    const int b    = blockIdx.x;
    const int h    = threadIdx.x;
    const int wv   = h >> 6;
    const int lane = h & 63;

    __shared__ unsigned long long zmS[2][4];
    __shared__ __align__(16) int listS[2][4][264];   // [parity][wave][entry], h<<10
    __shared__ float cntS[H_SZ];

    double v = 0.0, syn = 0.0;
    int cnt = 0;
    int nn[2] = {0, 0};

    const double* curb = cur + (size_t)b * H_SZ + h;
    const char*   wrb  = (const char*)WrTz;          // SGPR-uniform base
    const uint32_t hoff = (uint32_t)(h * 4);
    double inp_c = curb[0];                          // prefetch t=0

    for (int t = 0; t < T_STEPS; ++t) {
        const int p = t & 1;
        const int q = p ^ 1;
        // prefetch next step's input drive (full step of slack)
        int tn = (t < T_STEPS - 1) ? t + 1 : t;
        double inp_n = curb[(size_t)tn * B_SZ * H_SZ];

        // LIF dynamics, reference op order, fp64
        double v_dec = v + 0.05 * ((0.0 - v) + syn);
        double i_dec = 0.9 * syn;
        bool   z_new = v_dec > 0.5;
        v = z_new ? 0.0 : v_dec;
        cnt += z_new ? 1 : 0;

        // gather recurrent drive from this wave's private list (built last step)
        double r0 = 0.0, r1 = 0.0, r2 = 0.0, r3 = 0.0;
        const int* lp = listS[p][wv];
        const int  n  = nn[p];
        for (int j = 0; j < n; j += 8) {
            v4i w0 = *(const v4i*)(lp + j);
            v4i w1 = *(const v4i*)(lp + j + 4);
            float f0 = *(const float*)(wrb + ((uint32_t)w0.x + hoff));
            float f1 = *(const float*)(wrb + ((uint32_t)w0.y + hoff));
            float f2 = *(const float*)(wrb + ((uint32_t)w0.z + hoff));
            float f3 = *(const float*)(wrb + ((uint32_t)w0.w + hoff));
            float f4 = *(const float*)(wrb + ((uint32_t)w1.x + hoff));
            float f5 = *(const float*)(wrb + ((uint32_t)w1.y + hoff));
            float f6 = *(const float*)(wrb + ((uint32_t)w1.z + hoff));
            float f7 = *(const float*)(wrb + ((uint32_t)w1.w + hoff));
            r0 += (double)f0 + (double)f1;
            r1 += (double)f2 + (double)f3;
            r2 += (double)f4 + (double)f5;
            r3 += (double)f6 + (double)f7;
        }

        // publish new spike mask (ping-pong slot q)
        unsigned long long bal = __ballot((int)z_new);
        if (lane == 0) zmS[q][wv] = bal;
        __syncthreads();                             // the ONLY barrier per step

        // build this wave's private next-step list (ascending h, pre-scaled, padded)
        {
            unsigned long long m0 = zmS[q][0], m1 = zmS[q][1],
                               m2 = zmS[q][2], m3 = zmS[q][3];
            int c0 = __popcll(m0), c1 = __popcll(m1),
                c2 = __popcll(m2), c3 = __popcll(m3);
            const int wi = lane >> 4;                // word holding h=4*lane..4*lane+3
            unsigned long long word = zmS[q][wi];
            int basew = (wi > 0 ? c0 : 0) + (wi > 1 ? c1 : 0) + (wi > 2 ? c2 : 0);
            int* lw = listS[q][wv];
            const int hb = 4 * lane;
            #pragma unroll
            for (int u = 0; u < 4; ++u) {
                int bit = (hb + u) & 63;
                bool act = (word >> bit) & 1ull;
                int  pos = __popcll(word & ((1ull << bit) - 1ull));
                if (act) lw[basew + pos] = (hb + u) << 10;
            }
            int tot = c0 + c1 + c2 + c3;
            if (lane < 8) lw[tot + lane] = 256 << 10;   // pad -> zero row of WrTz
            nn[q] = tot;
        }

        syn = (i_dec + inp_c) + ((r0 + r1) + (r2 + r3));
        inp_c = inp_n;
        // no second barrier: private lists are same-wave in-order; zmS slot
        // reuse is separated by the next step's barrier.
    }

    cntS[h] = (float)cnt;
    __syncthreads();
    if (h < L_SZ) {
        double s = 0.0;
        for (int k = 0; k < H_SZ; ++k)
            s += (double)cntS[k] * (double)Wout[(size_t)h * H_SZ + k];
        s += (double)T_STEPS * (double)bout[h];
        out[(size_t)b * L_SZ + h] = (float)(s / (double)T_STEPS);
    }
}

// ---------------------------------------------------------------------------
extern "C" void kernel_launch(void* const* d_in, const int* in_sizes, int n_in,
                              void* d_out, int out_size, void* d_ws, size_t ws_size,
                              hipStream_t stream) {
    const float* x    = (const float*)d_in[0];   // [50,1024,784]
    const float* Wi   = (const float*)d_in[1];   // [256,784]
    const float* Wr   = (const float*)d_in[2];   // [256,256]
    const float* Wout = (const float*)d_in[3];   // [10,256]
    const float* bout = (const float*)d_in[4];   // [10]
    float* out = (float*)d_out;                  // [1024,10]

    // ws layout (~148.8 MB)
    char* ws = (char*)d_ws;
    double*  cur  = (double*)(ws);                       // 104,857,600 B
    float*   WrTz = (float*)(ws + 104857600);            // 257 rows x 256 x 4 = 263,168 B
    uint8_t* SBp  = (uint8_t*)(ws + 105121792);          //   1,064,960 B
    uint8_t* Ap   = (uint8_t*)(ws + 106186752);          //  42,598,400 B

    hipLaunchKernelGGL(prep_all, dim3(116), dim3(256), 0, stream, Wr, WrTz, Wi, SBp);
    hipLaunchKernelGGL(pack_x, dim3(M_TOT / 32), dim3(256), 0, stream, x, Ap);
    hipLaunchKernelGGL(gemm_i8s, dim3(1600), dim3(256), 0, stream, Ap, SBp, cur);
    hipLaunchKernelGGL(snn_scan, dim3(B_SZ), dim3(256), 0, stream,
                       cur, WrTz, Wout, bout, out);
}

// Round 9
// 377.499 us; speedup vs baseline: 1.0085x; 1.0085x over previous
//
#include <hip/hip_runtime.h>
#include <cstdint>
#include <cstddef>

#define T_STEPS 50
#define B_SZ    1024
#define N_INP   784
#define H_SZ    256
#define L_SZ    10
#define M_TOT   (T_STEPS * B_SZ)   // 51200
#define NK0     26                 // K padded to 26*32 = 832
#define NSLICE  5                  // 5 balanced base-256 digits of rint(Wi*2^40): exact (|Wi|<0.5)

typedef int v4i  __attribute__((ext_vector_type(4)));
typedef int v16i __attribute__((ext_vector_type(16)));

// ---------------------------------------------------------------------------
// Phase 0 (merged, R7): blocks 0..63 transpose Wr -> WrTz (+ zero row 256);
// blocks 64..115 pack Wi -> 5 balanced int8 digits (R5/R6-verified exact).
// ---------------------------------------------------------------------------
__global__ __launch_bounds__(256) void prep_all(const float* __restrict__ Wr,
                                                float* __restrict__ WrTz,
                                                const float* __restrict__ Wi,
                                                uint8_t* __restrict__ SBp) {
    const int blk = blockIdx.x;
    const int tid = threadIdx.x;
    if (blk < 64) {
        // ---- transpose Wr[h][k] (256x256) -> WrTz[k][h] ----
        __shared__ float tile[32][33];
        int bx = (blk & 7) * 32, by = (blk >> 3) * 32;
        int tx = tid % 32, ty = tid / 32;   // 32 x 8
        #pragma unroll
        for (int j = 0; j < 32; j += 8)
            tile[ty + j][tx] = Wr[(size_t)(by + ty + j) * H_SZ + bx + tx];
        if (blk == 0)
            WrTz[(size_t)256 * H_SZ + tid] = 0.0f;   // dummy zero row
        __syncthreads();
        #pragma unroll
        for (int j = 0; j < 32; j += 8)
            WrTz[(size_t)(bx + ty + j) * H_SZ + by + tx] = tile[tx][ty + j];
    } else {
        // ---- Wi -> digits, fragment-linear ----
        const int unit = (blk - 64) * 4 + (tid >> 6);   // 0..207 = (nt,k0)
        const int nt   = unit / 26;
        const int k0   = unit % 26;
        const int lane = tid & 63;
        const int h    = nt * 32 + (lane & 31);
        const int g    = k0 * 2 + (lane >> 5);          // 16-float group index

        int wd[NSLICE][4] = {};
        #pragma unroll
        for (int u = 0; u < 16; ++u) {
            double wv = 0.0;
            if (g < 49) wv = (double)Wi[(size_t)h * N_INP + g * 16 + u];
            double r = rint(wv * 0x1p40);
            #pragma unroll
            for (int j = 0; j < NSLICE - 1; ++j) {
                double q  = floor((r + 128.0) * 0.00390625);
                double dj = r - 256.0 * q;                     // in [-128,127]
                wd[j][u >> 2] |= ((int)dj & 0xFF) << ((u & 3) * 8);
                r = q;
            }
            wd[NSLICE - 1][u >> 2] |= ((int)r & 0xFF) << ((u & 3) * 8);
        }
        uint8_t* base = SBp + ((size_t)(nt * NK0 + k0) * NSLICE) * 1024 + lane * 16;
        #pragma unroll
        for (int j = 0; j < NSLICE; ++j)
            *(v4i*)(base + (size_t)j * 1024) = (v4i){wd[j][0], wd[j][1], wd[j][2], wd[j][3]};
    }
}

// ---------------------------------------------------------------------------
// Phase 0c: pack X (binary fp32) -> fragment-linear int8 (R6-verified).
// ---------------------------------------------------------------------------
__global__ __launch_bounds__(256) void pack_x(const float* __restrict__ X,
                                              uint8_t* __restrict__ Ap) {
    const int mt  = blockIdx.x;       // 1600
    const int tid = threadIdx.x;
    #pragma unroll
    for (int i = 0; i < 7; ++i) {
        int s = tid + i * 256;
        if (s < NK0 * 64) {
            int k0 = s >> 6, lane = s & 63;
            int m = mt * 32 + (lane & 31);
            int g = k0 * 2 + (lane >> 5);
            unsigned int bw[4] = {0u, 0u, 0u, 0u};
            if (g < 49) {
                const float* src = X + (size_t)m * N_INP + g * 16;
                #pragma unroll
                for (int q = 0; q < 4; ++q) {
                    float4 f = *(const float4*)(src + q * 4);
                    bw[q] = (f.x != 0.f ? 1u : 0u) | (f.y != 0.f ? 0x100u : 0u)
                          | (f.z != 0.f ? 0x10000u : 0u) | (f.w != 0.f ? 0x1000000u : 0u);
                }
            }
            *(v4i*)(Ap + ((size_t)(mt * NK0 + k0)) * 1024 + lane * 16) =
                (v4i){(int)bw[0], (int)bw[1], (int)bw[2], (int)bw[3]};
        }
    }
}

// ---------------------------------------------------------------------------
// Phase 1 (reverted to R6-verified best): cur = X @ Wi.T via 5 int8-digit
// MFMAs. B staged via global_load_lds width=16, 4-k0 double-buffered stages
// (2 x 20 KB LDS); __launch_bounds__(256,2) -> 2 blocks/CU; XCD-aware block
// swizzle (8 nt-sharers of one A-panel adjacent on one XCD -> L2 reuse).
// R7's 8-k0 stages regressed (longer load bursts) -> reverted.
// ---------------------------------------------------------------------------
typedef __attribute__((address_space(1))) uint32_t glds_g;
typedef __attribute__((address_space(3))) uint32_t glds_l;

#define STAGE_B(dstbuf, srcp, NI)                                               \
    {                                                                           \
        _Pragma("unroll")                                                       \
        for (int j_ = 0; j_ < (NI); ++j_) {                                     \
            int s_ = j_ * 256 + tid;                                            \
            __builtin_amdgcn_global_load_lds(                                   \
                (glds_g*)((srcp) + (size_t)s_ * 16),                            \
                (glds_l*)((dstbuf) + (size_t)s_ * 16), 16, 0, 0);               \
        }                                                                       \
    }

#define MFMA_STAGE(CB, A0, A1, NK)                                              \
    _Pragma("unroll")                                                           \
    for (int dk = 0; dk < (NK); ++dk) {                                         \
        _Pragma("unroll")                                                       \
        for (int j = 0; j < NSLICE; ++j) {                                      \
            v4i b = *(const v4i*)(Bs[CB] + (dk * NSLICE + j) * 1024 + lane * 16); \
            acc0[j] = __builtin_amdgcn_mfma_i32_32x32x32_i8(A0[dk], b, acc0[j], 0, 0, 0); \
            acc1[j] = __builtin_amdgcn_mfma_i32_32x32x32_i8(A1[dk], b, acc1[j], 0, 0, 0); \
        }                                                                       \
    }

__global__ __launch_bounds__(256, 2) void gemm_i8s(const uint8_t* __restrict__ Ap,
                                                   const uint8_t* __restrict__ SBp,
                                                   double* __restrict__ cur) {
    __shared__ __align__(16) uint8_t Bs[2][4 * NSLICE * 1024];   // 2 x 20 KB

    const int tid   = threadIdx.x;
    const int wave  = tid >> 6;
    const int lane  = tid & 63;
    const int ghalf = lane >> 5;

    // XCD-aware swizzle: id = xcd + 8*slot, slot = (x%25)*8 + nt -> xcd = x/25
    const int id   = blockIdx.x;          // 0..1599
    const int xcd  = id & 7;
    const int slot = id >> 3;             // 0..199
    const int x    = xcd * 25 + (slot >> 3);
    const int nt   = slot & 7;

    const int mt0   = (x * 4 + wave) * 2;     // wave owns mt0, mt0+1
    const int mt1   = mt0 + 1;

    const uint8_t* ap0 = Ap + (size_t)mt0 * NK0 * 1024 + lane * 16;
    const uint8_t* ap1 = Ap + (size_t)mt1 * NK0 * 1024 + lane * 16;
    const uint8_t* bbase = SBp + ((size_t)nt * NK0 * NSLICE) * 1024;

    v4i a0[4], a1[4], n0[4], n1[4];

    // prologue: stage stage-0 (k0 0..3), prefetch its A fragments
    STAGE_B(Bs[0], bbase, 5);
    #pragma unroll
    for (int dk = 0; dk < 4; ++dk) {
        a0[dk] = *(const v4i*)(ap0 + (size_t)dk * 1024);
        a1[dk] = *(const v4i*)(ap1 + (size_t)dk * 1024);
    }
    __syncthreads();                       // vmcnt(0): stage-0 resident

    v16i acc0[NSLICE] = {};
    v16i acc1[NSLICE] = {};

    for (int s = 0; s < 6; ++s) {
        const int cb = s & 1;
        if (s < 5) {                       // full next stage: 4 k0, 20 KB
            STAGE_B(Bs[cb ^ 1], bbase + (size_t)(s + 1) * 20480, 5);
            #pragma unroll
            for (int dk = 0; dk < 4; ++dk) {
                n0[dk] = *(const v4i*)(ap0 + (size_t)((s + 1) * 4 + dk) * 1024);
                n1[dk] = *(const v4i*)(ap1 + (size_t)((s + 1) * 4 + dk) * 1024);
            }
        } else {                           // tail stage: k0 24..25 (+pad)
            STAGE_B(Bs[cb ^ 1], bbase + (size_t)6 * 20480, 3);
            #pragma unroll
            for (int dk = 0; dk < 2; ++dk) {
                n0[dk] = *(const v4i*)(ap0 + (size_t)(24 + dk) * 1024);
                n1[dk] = *(const v4i*)(ap1 + (size_t)(24 + dk) * 1024);
            }
        }
        MFMA_STAGE(cb, a0, a1, 4);
        __syncthreads();                   // next stage resident; cb free to reuse
        #pragma unroll
        for (int dk = 0; dk < 4; ++dk) { a0[dk] = n0[dk]; a1[dk] = n1[dk]; }
    }
    MFMA_STAGE(0, a0, a1, 2);              // tail: k0 24..25 in Bs[0]

    // recombine digits (exact integer Horner in fp64) and store both m-tiles
    const int h = nt * 32 + (lane & 31);
    #pragma unroll
    for (int r = 0; r < 16; ++r) {
        int mloc = (r & 3) + 8 * (r >> 2) + 4 * ghalf;
        double s0 = (double)acc0[4][r];
        s0 = s0 * 256.0 + (double)acc0[3][r];
        s0 = s0 * 256.0 + (double)acc0[2][r];
        s0 = s0 * 256.0 + (double)acc0[1][r];
        s0 = s0 * 256.0 + (double)acc0[0][r];
        cur[(size_t)(mt0 * 32 + mloc) * H_SZ + h] = s0 * 0x1p-40;
        double s1 = (double)acc1[4][r];
        s1 = s1 * 256.0 + (double)acc1[3][r];
        s1 = s1 * 256.0 + (double)acc1[2][r];
        s1 = s1 * 256.0 + (double)acc1[1][r];
        s1 = s1 * 256.0 + (double)acc1[0][r];
        cur[(size_t)(mt1 * 32 + mloc) * H_SZ + h] = s1 * 0x1p-40;
    }
}

// ---------------------------------------------------------------------------
// Phase 2 (v2, locked — best measured scan, ~88 µs; three restructures all
// regressed): 50 LIF steps fp64, block = batch (256 thr = 4 waves). ONE
// barrier per step: ballot masks ping-pong; each wave builds a PRIVATE padded
// spike list; entries pre-scaled to row byte offsets; 2x ds_read_b128 per 8.
// ---------------------------------------------------------------------------
__global__ __launch_bounds__(256) void snn_scan(const double* __restrict__ cur,
                                                const float* __restrict__ WrTz,
                                                const float* __restrict__ Wout,
                                                const float* __restrict__ bout,
                                                float* __restrict__ out) {
    const int b    = blockIdx.x;
    const int h    = threadIdx.x;
    const int wv   = h >> 6;
    const int lane = h & 63;

    __shared__ unsigned long long zmS[2][4];
    __shared__ __align__(16) int listS[2][4][264];   // [parity][wave][entry], h<<10
    __shared__ float cntS[H_SZ];

    double v = 0.0, syn = 0.0;
    int cnt = 0;
    int nn[2] = {0, 0};

    const double* curb = cur + (size_t)b * H_SZ + h;
    const char*   wrb  = (const char*)WrTz;          // SGPR-uniform base
    const uint32_t hoff = (uint32_t)(h * 4);
    double inp_c = curb[0];                          // prefetch t=0

    for (int t = 0; t < T_STEPS; ++t) {
        const int p = t & 1;
        const int q = p ^ 1;
        // prefetch next step's input drive (full step of slack)
        int tn = (t < T_STEPS - 1) ? t + 1 : t;
        double inp_n = curb[(size_t)tn * B_SZ * H_SZ];

        // LIF dynamics, reference op order, fp64
        double v_dec = v + 0.05 * ((0.0 - v) + syn);
        double i_dec = 0.9 * syn;
        bool   z_new = v_dec > 0.5;
        v = z_new ? 0.0 : v_dec;
        cnt += z_new ? 1 : 0;

        // gather recurrent drive from this wave's private list (built last step)
        double r0 = 0.0, r1 = 0.0, r2 = 0.0, r3 = 0.0;
        const int* lp = listS[p][wv];
        const int  n  = nn[p];
        for (int j = 0; j < n; j += 8) {
            v4i w0 = *(const v4i*)(lp + j);
            v4i w1 = *(const v4i*)(lp + j + 4);
            float f0 = *(const float*)(wrb + ((uint32_t)w0.x + hoff));
            float f1 = *(const float*)(wrb + ((uint32_t)w0.y + hoff));
            float f2 = *(const float*)(wrb + ((uint32_t)w0.z + hoff));
            float f3 = *(const float*)(wrb + ((uint32_t)w0.w + hoff));
            float f4 = *(const float*)(wrb + ((uint32_t)w1.x + hoff));
            float f5 = *(const float*)(wrb + ((uint32_t)w1.y + hoff));
            float f6 = *(const float*)(wrb + ((uint32_t)w1.z + hoff));
            float f7 = *(const float*)(wrb + ((uint32_t)w1.w + hoff));
            r0 += (double)f0 + (double)f1;
            r1 += (double)f2 + (double)f3;
            r2 += (double)f4 + (double)f5;
            r3 += (double)f6 + (double)f7;
        }

        // publish new spike mask (ping-pong slot q)
        unsigned long long bal = __ballot((int)z_new);
        if (lane == 0) zmS[q][wv] = bal;
        __syncthreads();                             // the ONLY barrier per step

        // build this wave's private next-step list (ascending h, pre-scaled, padded)
        {
            unsigned long long m0 = zmS[q][0], m1 = zmS[q][1],
                               m2 = zmS[q][2], m3 = zmS[q][3];
            int c0 = __popcll(m0), c1 = __popcll(m1),
                c2 = __popcll(m2), c3 = __popcll(m3);
            const int wi = lane >> 4;                // word holding h=4*lane..4*lane+3
            unsigned long long word = zmS[q][wi];
            int basew = (wi > 0 ? c0 : 0) + (wi > 1 ? c1 : 0) + (wi > 2 ? c2 : 0);
            int* lw = listS[q][wv];
            const int hb = 4 * lane;
            #pragma unroll
            for (int u = 0; u < 4; ++u) {
                int bit = (hb + u) & 63;
                bool act = (word >> bit) & 1ull;
                int  pos = __popcll(word & ((1ull << bit) - 1ull));
                if (act) lw[basew + pos] = (hb + u) << 10;
            }
            int tot = c0 + c1 + c2 + c3;
            if (lane < 8) lw[tot + lane] = 256 << 10;   // pad -> zero row of WrTz
            nn[q] = tot;
        }

        syn = (i_dec + inp_c) + ((r0 + r1) + (r2 + r3));
        inp_c = inp_n;
        // no second barrier: private lists are same-wave in-order; zmS slot
        // reuse is separated by the next step's barrier.
    }

    cntS[h] = (float)cnt;
    __syncthreads();
    if (h < L_SZ) {
        double s = 0.0;
        for (int k = 0; k < H_SZ; ++k)
            s += (double)cntS[k] * (double)Wout[(size_t)h * H_SZ + k];
        s += (double)T_STEPS * (double)bout[h];
        out[(size_t)b * L_SZ + h] = (float)(s / (double)T_STEPS);
    }
}

// ---------------------------------------------------------------------------
extern "C" void kernel_launch(void* const* d_in, const int* in_sizes, int n_in,
                              void* d_out, int out_size, void* d_ws, size_t ws_size,
                              hipStream_t stream) {
    const float* x    = (const float*)d_in[0];   // [50,1024,784]
    const float* Wi   = (const float*)d_in[1];   // [256,784]
    const float* Wr   = (const float*)d_in[2];   // [256,256]
    const float* Wout = (const float*)d_in[3];   // [10,256]
    const float* bout = (const float*)d_in[4];   // [10]
    float* out = (float*)d_out;                  // [1024,10]

    // ws layout (~148.8 MB)
    char* ws = (char*)d_ws;
    double*  cur  = (double*)(ws);                       // 104,857,600 B
    float*   WrTz = (float*)(ws + 104857600);            // 257 rows x 256 x 4 = 263,168 B
    uint8_t* SBp  = (uint8_t*)(ws + 105121792);          //   1,064,960 B
    uint8_t* Ap   = (uint8_t*)(ws + 106186752);          //  42,598,400 B

    hipLaunchKernelGGL(prep_all, dim3(116), dim3(256), 0, stream, Wr, WrTz, Wi, SBp);
    hipLaunchKernelGGL(pack_x, dim3(M_TOT / 32), dim3(256), 0, stream, x, Ap);
    hipLaunchKernelGGL(gemm_i8s, dim3(1600), dim3(256), 0, stream, Ap, SBp, cur);
    hipLaunchKernelGGL(snn_scan, dim3(B_SZ), dim3(256), 0, stream,
                       cur, WrTz, Wout, bout, out);
}